// Round 1
// 814.784 us; speedup vs baseline: 1.0826x; 1.0826x over previous
//
#include <hip/hip_runtime.h>

#define BATCH 16
#define LSEQ  2048
#define DDIM  128
#define EPSV  1e-12f
#define NTILE (LSEQ / 64)          // 32 stat-tiles per dim (64-granularity, unchanged)
#define NROWS (BATCH * LSEQ)       // 32768

typedef __attribute__((ext_vector_type(4))) float f32x4;
typedef __attribute__((ext_vector_type(8))) __bf16 bf16x8;
typedef __attribute__((ext_vector_type(8))) unsigned short u16x8;

// fp32 -> bf16 round-to-nearest-even (finite inputs)
__device__ __forceinline__ unsigned short f2bf(float x) {
    unsigned int u = __float_as_uint(x);
    u += 0x7FFFu + ((u >> 16) & 1u);
    return (unsigned short)(u >> 16);
}
__device__ __forceinline__ float bf2f(unsigned short h) {
    return __uint_as_float(((unsigned int)h) << 16);
}

// swizzled offset within a [128 rows][64 cols] ushort plane (row = 128B = 8 x 16B slots)
// slot' = slot ^ (row&7): spreads the 16 lanes of a fragment read across all banks.
__device__ __forceinline__ int swz(int row, int col8) {   // col8 is 8-aligned
    return (row << 6) + ((((col8 >> 3) ^ row) & 7) << 3);
}

// ---------------------------------------------------------------------------
// K1: attn = Q K^T via bf16x3-split MFMA (hi*hi + hi*lo + lo*hi), 128x128
// tile/block, 4 waves (2x2), each wave owns one 64x64 stat tile.  Fused
// per-tile softmax stats (row/col max, masked exp-sums), layout identical to
// the previous kernel so K2/K3 are unchanged.
// ---------------------------------------------------------------------------
__global__ __launch_bounds__(256, 2) void k1_qk_stats(
    const float* __restrict__ q, const float* __restrict__ kmat,
    const float* __restrict__ mask, float* __restrict__ attn,
    float* __restrict__ rowMt, float* __restrict__ rowSt,
    float* __restrict__ colMt, float* __restrict__ colSt)
{
    const int b  = blockIdx.z;
    const int it = blockIdx.y * 128;
    const int jt = blockIdx.x * 128;

    __shared__ __attribute__((aligned(16))) unsigned short smem[4 * 128 * 64]; // 64 KB
    unsigned short* Ah = smem;
    unsigned short* Al = smem + 128 * 64;
    unsigned short* Bh = smem + 2 * 128 * 64;
    unsigned short* Bl = smem + 3 * 128 * 64;

    const int tid  = threadIdx.x;
    const int lane = tid & 63;
    const int w    = tid >> 6;
    const int wrow = (w >> 1) << 6;        // 0 or 64
    const int wcol = (w & 1) << 6;         // 0 or 64
    const int g    = lane >> 4;            // 0..3
    const int cl   = lane & 15;            // 0..15

    const float* qb = q    + ((size_t)b * LSEQ + it) * DDIM;
    const float* kb = kmat + ((size_t)b * LSEQ + jt) * DDIM;

    // staging: thread loads rows (lr, lr+64), 16 consecutive floats at col lc
    const int lr = tid >> 2;               // 0..63
    const int lc = (tid & 3) << 4;         // 0,16,32,48

    f32x4 acc[4][4];
    const f32x4 zero = {0.f, 0.f, 0.f, 0.f};
#pragma unroll
    for (int i = 0; i < 4; ++i)
#pragma unroll
        for (int j = 0; j < 4; ++j) acc[i][j] = zero;

    for (int ks2 = 0; ks2 < DDIM; ks2 += 64) {
        if (ks2) __syncthreads();          // previous stage fully consumed
#pragma unroll
        for (int pr = 0; pr < 2; ++pr) {
            const int row = lr + (pr << 6);
            const float* qr = qb + (size_t)row * DDIM + ks2 + lc;
            const float* kr = kb + (size_t)row * DDIM + ks2 + lc;
#pragma unroll
            for (int cc = 0; cc < 16; cc += 8) {
                float xs[8], ys[8];
                *(float4*)&xs[0] = *(const float4*)(qr + cc);
                *(float4*)&xs[4] = *(const float4*)(qr + cc + 4);
                *(float4*)&ys[0] = *(const float4*)(kr + cc);
                *(float4*)&ys[4] = *(const float4*)(kr + cc + 4);
                u16x8 qh, ql, kh, kl;
#pragma unroll
                for (int e = 0; e < 8; ++e) {
                    const unsigned short h0 = f2bf(xs[e]);
                    qh[e] = h0;
                    ql[e] = f2bf(xs[e] - bf2f(h0));
                    const unsigned short h1 = f2bf(ys[e]);
                    kh[e] = h1;
                    kl[e] = f2bf(ys[e] - bf2f(h1));
                }
                const int o = swz(row, lc + cc);
                *(u16x8*)&Ah[o] = qh;
                *(u16x8*)&Al[o] = ql;
                *(u16x8*)&Bh[o] = kh;
                *(u16x8*)&Bl[o] = kl;
            }
        }
        __syncthreads();

#pragma unroll
        for (int ks = 0; ks < 64; ks += 32) {
            const int colb = ks + (g << 3);      // frag k-base for this lane
            bf16x8 ah[4], al[4], bh[4], bl[4];
#pragma unroll
            for (int f = 0; f < 4; ++f) {
                const int ra = wrow + (f << 4) + cl;   // A row  (m = lane&15)
                const int rb = wcol + (f << 4) + cl;   // B col  (n = lane&15)
                ah[f] = __builtin_bit_cast(bf16x8, *(const u16x8*)&Ah[swz(ra, colb)]);
                al[f] = __builtin_bit_cast(bf16x8, *(const u16x8*)&Al[swz(ra, colb)]);
                bh[f] = __builtin_bit_cast(bf16x8, *(const u16x8*)&Bh[swz(rb, colb)]);
                bl[f] = __builtin_bit_cast(bf16x8, *(const u16x8*)&Bl[swz(rb, colb)]);
            }
#pragma unroll
            for (int fr = 0; fr < 4; ++fr)
#pragma unroll
                for (int fc = 0; fc < 4; ++fc) {
                    acc[fr][fc] = __builtin_amdgcn_mfma_f32_16x16x32_bf16(ah[fr], bh[fc], acc[fr][fc], 0, 0, 0);
                    acc[fr][fc] = __builtin_amdgcn_mfma_f32_16x16x32_bf16(ah[fr], bl[fc], acc[fr][fc], 0, 0, 0);
                    acc[fr][fc] = __builtin_amdgcn_mfma_f32_16x16x32_bf16(al[fr], bh[fc], acc[fr][fc], 0, 0, 0);
                }
        }
    }

    // ---- epilogue: attn store + per-64x64-tile stats (pure shuffles) ----
    // C/D layout: col = lane&15 (cl), row = g*4 + reg, per 16x16 fragment.
    const size_t grow0 = (size_t)b * LSEQ + it + wrow;
    float*       arow  = attn + grow0 * LSEQ + jt + wcol;
    const float* mrow  = mask + grow0 * LSEQ + jt + wcol;

    // col maxes: lane owns col fc*16+cl; reduce over in-lane rows then g-groups
    float colm[4];
#pragma unroll
    for (int fc = 0; fc < 4; ++fc) {
        float m = acc[0][fc][0];
#pragma unroll
        for (int fr = 0; fr < 4; ++fr)
#pragma unroll
            for (int r = 0; r < 4; ++r) m = fmaxf(m, acc[fr][fc][r]);
        m = fmaxf(m, __shfl_xor(m, 16, 64));
        m = fmaxf(m, __shfl_xor(m, 32, 64));
        colm[fc] = m;
    }
    // row maxes: reduce over fc then the 16 cl-lanes (butterfly -> broadcast)
    float rowm[4][4];
#pragma unroll
    for (int fr = 0; fr < 4; ++fr)
#pragma unroll
        for (int r = 0; r < 4; ++r) {
            float m = fmaxf(fmaxf(acc[fr][0][r], acc[fr][1][r]),
                            fmaxf(acc[fr][2][r], acc[fr][3][r]));
            m = fmaxf(m, __shfl_xor(m, 1, 64));
            m = fmaxf(m, __shfl_xor(m, 2, 64));
            m = fmaxf(m, __shfl_xor(m, 4, 64));
            m = fmaxf(m, __shfl_xor(m, 8, 64));
            rowm[fr][r] = m;
        }

    float cols_[4] = {0.f, 0.f, 0.f, 0.f};
    float rows_[4][4];
#pragma unroll
    for (int fr = 0; fr < 4; ++fr) {
#pragma unroll
        for (int r = 0; r < 4; ++r) {
            const int R = (fr << 4) + (g << 2) + r;
            float rs = 0.f;
#pragma unroll
            for (int fc = 0; fc < 4; ++fc) {
                const int C = (fc << 4) + cl;
                const float x = acc[fr][fc][r];
                arow[(size_t)R * LSEQ + C] = x;
                const float mk = mrow[(size_t)R * LSEQ + C];
                rs        += __expf(x - rowm[fr][r]) * mk;
                cols_[fc] += __expf(x - colm[fc])    * mk;
            }
            rs += __shfl_xor(rs, 1, 64);
            rs += __shfl_xor(rs, 2, 64);
            rs += __shfl_xor(rs, 4, 64);
            rs += __shfl_xor(rs, 8, 64);
            rows_[fr][r] = rs;
        }
    }
#pragma unroll
    for (int fc = 0; fc < 4; ++fc) {
        float s = cols_[fc];
        s += __shfl_xor(s, 16, 64);
        s += __shfl_xor(s, 32, 64);
        cols_[fc] = s;
    }

    // stats writes (wave tile == one 64x64 stat tile; same layout as before)
    const int ti = (blockIdx.y << 1) + (w >> 1);
    const int tj = (blockIdx.x << 1) + (w & 1);
    if (cl == 0) {
        const size_t rbase = (size_t)tj * NROWS + (size_t)b * LSEQ + it + wrow;
#pragma unroll
        for (int fr = 0; fr < 4; ++fr)
#pragma unroll
            for (int r = 0; r < 4; ++r) {
                const int R = (fr << 4) + (g << 2) + r;
                rowMt[rbase + R] = rowm[fr][r];
                rowSt[rbase + R] = rows_[fr][r];
            }
    }
    if (g == 0) {
        const size_t cbase = (size_t)ti * NROWS + (size_t)b * LSEQ + jt + wcol;
#pragma unroll
        for (int fc = 0; fc < 4; ++fc) {
            colMt[cbase + (fc << 4) + cl] = colm[fc];
            colSt[cbase + (fc << 4) + cl] = cols_[fc];
        }
    }
}

// ---------------------------------------------------------------------------
// K2: combine per-tile stats -> global max & sum per row / col. (unchanged)
// ---------------------------------------------------------------------------
__global__ __launch_bounds__(256) void k2_combine(
    const float* __restrict__ rowMt, const float* __restrict__ rowSt,
    const float* __restrict__ colMt, const float* __restrict__ colSt,
    float* __restrict__ rmaxf, float* __restrict__ rsumf,
    float* __restrict__ cmaxf, float* __restrict__ csumf)
{
    const int id = blockIdx.x * 256 + threadIdx.x;   // [0, 2*NROWS)
    const bool isRow = (id < NROWS);
    const int off = isRow ? id : id - NROWS;
    const float* Mt = isRow ? rowMt : colMt;
    const float* St = isRow ? rowSt : colSt;

    float m = -INFINITY;
#pragma unroll
    for (int t = 0; t < NTILE; ++t) m = fmaxf(m, Mt[(size_t)t * NROWS + off]);
    float s = 0.f;
#pragma unroll
    for (int t = 0; t < NTILE; ++t)
        s += St[(size_t)t * NROWS + off] * __expf(Mt[(size_t)t * NROWS + off] - m);

    if (isRow) { rmaxf[off] = m; rsumf[off] = s; }
    else       { cmaxf[off] = m; csumf[off] = s; }
}

// ---------------------------------------------------------------------------
// K3: gated = mask*exp(2x - m_row - m_col)/((sr+eps)(sc+eps)) in place over
// attn, fused with out = gated @ v. (unchanged)
// ---------------------------------------------------------------------------
__global__ __launch_bounds__(256) void k3_gated_out(
    const float* __restrict__ mask, const float* __restrict__ v,
    const float* __restrict__ rmaxf, const float* __restrict__ cmaxf,
    const float* __restrict__ rsumf, const float* __restrict__ csumf,
    float* __restrict__ gated, float* __restrict__ outp)
{
    const int b   = blockIdx.y;
    const int it0 = blockIdx.x * 32;

    __shared__ float Gs[32][36];     // gated chunk, transposed [j][i]
    __shared__ float Vs[32][128];    // v chunk [j][dv]
    __shared__ float RowM[32], RowIS[32];
    __shared__ float ColM[32], ColIS[32];

    const int tid = threadIdx.x;
    if (tid < 32) {
        RowM[tid]  = rmaxf[b * LSEQ + it0 + tid];
        RowIS[tid] = 1.f / (rsumf[b * LSEQ + it0 + tid] + EPSV);
    }

    const int r0  = (tid >> 5) << 2;  // out rows 0..28
    const int c0  = (tid & 31) << 2;  // out cols 0..124
    const int gr  = tid >> 3;         // gated row 0..31
    const int gc4 = (tid & 7) << 2;   // gated col-in-chunk
    const int vr  = tid >> 5;         // v loader row 0..7 (+8p)
    const int vc  = (tid & 31) << 2;  // v loader col

    float acc[4][4];
#pragma unroll
    for (int u = 0; u < 4; ++u)
#pragma unroll
        for (int w = 0; w < 4; ++w) acc[u][w] = 0.f;

    const float* mb = mask  + ((size_t)b * LSEQ + it0) * LSEQ;
    float*       gb = gated + ((size_t)b * LSEQ + it0) * LSEQ;
    const float* vb = v + (size_t)b * LSEQ * DDIM;

    float4 xpre = *(const float4*)(gb + (size_t)gr * LSEQ + gc4);
    float4 mpre = *(const float4*)(mb + (size_t)gr * LSEQ + gc4);

    for (int j0 = 0; j0 < LSEQ; j0 += 32) {
        __syncthreads();   // previous chunk fully consumed
        if (tid < 32) {
            ColM[tid]  = cmaxf[b * LSEQ + j0 + tid];
            ColIS[tid] = 1.f / (csumf[b * LSEQ + j0 + tid] + EPSV);
        }
#pragma unroll
        for (int p = 0; p < 4; ++p) {
            const int row = vr + p * 8;
            *(float4*)&Vs[row][vc] = *(const float4*)(vb + (size_t)(j0 + row) * DDIM + vc);
        }
        __syncthreads();   // ColM/ColIS + Vs visible

        float4 xc = xpre, mk = mpre;
        if (j0 + 32 < LSEQ) {
            xpre = *(const float4*)(gb + (size_t)gr * LSEQ + j0 + 32 + gc4);
            mpre = *(const float4*)(mb + (size_t)gr * LSEQ + j0 + 32 + gc4);
        }
        {
            const float mrw = RowM[gr], isr = RowIS[gr];
            float g0 = mk.x * __expf(2.f * xc.x - mrw - ColM[gc4 + 0]) * isr * ColIS[gc4 + 0];
            float g1 = mk.y * __expf(2.f * xc.y - mrw - ColM[gc4 + 1]) * isr * ColIS[gc4 + 1];
            float g2 = mk.z * __expf(2.f * xc.z - mrw - ColM[gc4 + 2]) * isr * ColIS[gc4 + 2];
            float g3 = mk.w * __expf(2.f * xc.w - mrw - ColM[gc4 + 3]) * isr * ColIS[gc4 + 3];
            *(float4*)(gb + (size_t)gr * LSEQ + j0 + gc4) = make_float4(g0, g1, g2, g3);
            Gs[gc4 + 0][gr] = g0; Gs[gc4 + 1][gr] = g1;
            Gs[gc4 + 2][gr] = g2; Gs[gc4 + 3][gr] = g3;
        }
        __syncthreads();   // Gs ready
#pragma unroll
        for (int kk = 0; kk < 32; ++kk) {
            float4 a4 = *(const float4*)&Gs[kk][r0];
            float4 b4 = *(const float4*)&Vs[kk][c0];
            float av[4] = {a4.x, a4.y, a4.z, a4.w};
            float bv[4] = {b4.x, b4.y, b4.z, b4.w};
#pragma unroll
            for (int u = 0; u < 4; ++u)
#pragma unroll
                for (int w = 0; w < 4; ++w)
                    acc[u][w] = fmaf(av[u], bv[w], acc[u][w]);
        }
    }

    float* ob = outp + ((size_t)b * LSEQ + it0) * DDIM;
#pragma unroll
    for (int u = 0; u < 4; ++u)
        *(float4*)(ob + (size_t)(r0 + u) * DDIM + c0) =
            make_float4(acc[u][0], acc[u][1], acc[u][2], acc[u][3]);
}

// ---------------------------------------------------------------------------
extern "C" void kernel_launch(void* const* d_in, const int* in_sizes, int n_in,
                              void* d_out, int out_size, void* d_ws, size_t ws_size,
                              hipStream_t stream)
{
    (void)in_sizes; (void)n_in; (void)out_size; (void)ws_size;
    const float* q    = (const float*)d_in[0];
    const float* k    = (const float*)d_in[1];
    const float* v    = (const float*)d_in[2];
    const float* mask = (const float*)d_in[3];

    float* outp  = (float*)d_out;                                   // B*L*D
    float* gated = (float*)d_out + (size_t)BATCH * LSEQ * DDIM;     // B*L*L

    float* rowMt = (float*)d_ws;                 // [NTILE][NROWS]
    float* rowSt = rowMt + (size_t)NTILE * NROWS;
    float* colMt = rowSt + (size_t)NTILE * NROWS;
    float* colSt = colMt + (size_t)NTILE * NROWS;
    float* rmaxf = colSt + (size_t)NTILE * NROWS;
    float* rsumf = rmaxf + NROWS;
    float* cmaxf = rsumf + NROWS;
    float* csumf = cmaxf + NROWS;

    dim3 g1(LSEQ / 128, LSEQ / 128, BATCH);
    k1_qk_stats<<<g1, dim3(256), 0, stream>>>(q, k, mask, gated,
                                              rowMt, rowSt, colMt, colSt);

    k2_combine<<<dim3(2 * NROWS / 256), dim3(256), 0, stream>>>(
        rowMt, rowSt, colMt, colSt, rmaxf, rsumf, cmaxf, csumf);

    dim3 g3(LSEQ / 32, BATCH);
    k3_gated_out<<<g3, dim3(256), 0, stream>>>(mask, v, rmaxf, cmaxf,
                                               rsumf, csumf, gated, outp);
}

// Round 2
// 751.345 us; speedup vs baseline: 1.1740x; 1.0844x over previous
//
#include <hip/hip_runtime.h>

#define BATCH 16
#define LSEQ  2048
#define DDIM  128
#define EPSV  1e-12f
#define NTILE (LSEQ / 64)          // 32 stat-tiles per dim (64-granularity, unchanged)
#define NROWS (BATCH * LSEQ)       // 32768

typedef __attribute__((ext_vector_type(4))) float f32x4;
typedef __attribute__((ext_vector_type(8))) __bf16 bf16x8;
typedef __attribute__((ext_vector_type(8))) unsigned short u16x8;

// fp32 -> bf16 round-to-nearest-even (finite inputs)
__device__ __forceinline__ unsigned short f2bf(float x) {
    unsigned int u = __float_as_uint(x);
    u += 0x7FFFu + ((u >> 16) & 1u);
    return (unsigned short)(u >> 16);
}
__device__ __forceinline__ float bf2f(unsigned short h) {
    return __uint_as_float(((unsigned int)h) << 16);
}

// swizzled offset within a [rows][64 cols] ushort plane (row = 128B = 8 x 16B slots)
__device__ __forceinline__ int swz(int row, int col8) {   // col8 is 8-aligned
    return (row << 6) + ((((col8 >> 3) ^ row) & 7) << 3);
}

// ---------------------------------------------------------------------------
// K0: V[b][j][dv] -> Vt planes (bf16 hi/lo) [b][dv][j], for MFMA B-operand
// (needs 8 consecutive j per lane at fixed dv).
// ---------------------------------------------------------------------------
__global__ __launch_bounds__(256) void k0_vtrans(
    const float* __restrict__ v,
    unsigned short* __restrict__ vth, unsigned short* __restrict__ vtl)
{
    const int b  = blockIdx.z;
    const int j0 = blockIdx.x * 64;
    const int d0 = blockIdx.y * 64;
    __shared__ float T[64][65];

    const int tid = threadIdx.x;
    {
        const int jr = tid >> 4;             // 0..15 (+16p)
        const int c4 = (tid & 15) << 2;      // 0..60
#pragma unroll
        for (int p = 0; p < 4; ++p) {
            const int row = jr + (p << 4);
            *(float4*)&T[row][c4] =
                *(const float4*)(v + ((size_t)b * LSEQ + j0 + row) * DDIM + d0 + c4);
        }
    }
    __syncthreads();

    const int dr = tid >> 2;                 // 0..63 (dv within tile)
    const int jc = (tid & 3) << 4;           // 0,16,32,48
    u16x8 h[2], l[2];
#pragma unroll
    for (int e = 0; e < 16; ++e) {
        const float x = T[jc + e][dr];
        const unsigned short hh = f2bf(x);
        h[e >> 3][e & 7] = hh;
        l[e >> 3][e & 7] = f2bf(x - bf2f(hh));
    }
    unsigned short* oh = vth + ((size_t)b * DDIM + d0 + dr) * LSEQ + j0 + jc;
    unsigned short* ol = vtl + ((size_t)b * DDIM + d0 + dr) * LSEQ + j0 + jc;
    *(u16x8*)oh = h[0]; *(u16x8*)(oh + 8) = h[1];
    *(u16x8*)ol = l[0]; *(u16x8*)(ol + 8) = l[1];
}

// ---------------------------------------------------------------------------
// K1: attn = Q K^T via bf16x3-split MFMA (hi*hi + hi*lo + lo*hi), 128x128
// tile/block, 4 waves (2x2), each wave owns one 64x64 stat tile. (unchanged)
// ---------------------------------------------------------------------------
__global__ __launch_bounds__(256, 2) void k1_qk_stats(
    const float* __restrict__ q, const float* __restrict__ kmat,
    const float* __restrict__ mask, float* __restrict__ attn,
    float* __restrict__ rowMt, float* __restrict__ rowSt,
    float* __restrict__ colMt, float* __restrict__ colSt)
{
    const int b  = blockIdx.z;
    const int it = blockIdx.y * 128;
    const int jt = blockIdx.x * 128;

    __shared__ __attribute__((aligned(16))) unsigned short smem[4 * 128 * 64]; // 64 KB
    unsigned short* Ah = smem;
    unsigned short* Al = smem + 128 * 64;
    unsigned short* Bh = smem + 2 * 128 * 64;
    unsigned short* Bl = smem + 3 * 128 * 64;

    const int tid  = threadIdx.x;
    const int lane = tid & 63;
    const int w    = tid >> 6;
    const int wrow = (w >> 1) << 6;        // 0 or 64
    const int wcol = (w & 1) << 6;         // 0 or 64
    const int g    = lane >> 4;            // 0..3
    const int cl   = lane & 15;            // 0..15

    const float* qb = q    + ((size_t)b * LSEQ + it) * DDIM;
    const float* kb = kmat + ((size_t)b * LSEQ + jt) * DDIM;

    const int lr = tid >> 2;               // 0..63
    const int lc = (tid & 3) << 4;         // 0,16,32,48

    f32x4 acc[4][4];
    const f32x4 zero = {0.f, 0.f, 0.f, 0.f};
#pragma unroll
    for (int i = 0; i < 4; ++i)
#pragma unroll
        for (int j = 0; j < 4; ++j) acc[i][j] = zero;

    for (int ks2 = 0; ks2 < DDIM; ks2 += 64) {
        if (ks2) __syncthreads();
#pragma unroll
        for (int pr = 0; pr < 2; ++pr) {
            const int row = lr + (pr << 6);
            const float* qr = qb + (size_t)row * DDIM + ks2 + lc;
            const float* kr = kb + (size_t)row * DDIM + ks2 + lc;
#pragma unroll
            for (int cc = 0; cc < 16; cc += 8) {
                float xs[8], ys[8];
                *(float4*)&xs[0] = *(const float4*)(qr + cc);
                *(float4*)&xs[4] = *(const float4*)(qr + cc + 4);
                *(float4*)&ys[0] = *(const float4*)(kr + cc);
                *(float4*)&ys[4] = *(const float4*)(kr + cc + 4);
                u16x8 qh, ql, kh, kl;
#pragma unroll
                for (int e = 0; e < 8; ++e) {
                    const unsigned short h0 = f2bf(xs[e]);
                    qh[e] = h0;
                    ql[e] = f2bf(xs[e] - bf2f(h0));
                    const unsigned short h1 = f2bf(ys[e]);
                    kh[e] = h1;
                    kl[e] = f2bf(ys[e] - bf2f(h1));
                }
                const int o = swz(row, lc + cc);
                *(u16x8*)&Ah[o] = qh;
                *(u16x8*)&Al[o] = ql;
                *(u16x8*)&Bh[o] = kh;
                *(u16x8*)&Bl[o] = kl;
            }
        }
        __syncthreads();

#pragma unroll
        for (int ks = 0; ks < 64; ks += 32) {
            const int colb = ks + (g << 3);
            bf16x8 ah[4], al[4], bh[4], bl[4];
#pragma unroll
            for (int f = 0; f < 4; ++f) {
                const int ra = wrow + (f << 4) + cl;
                const int rb = wcol + (f << 4) + cl;
                ah[f] = __builtin_bit_cast(bf16x8, *(const u16x8*)&Ah[swz(ra, colb)]);
                al[f] = __builtin_bit_cast(bf16x8, *(const u16x8*)&Al[swz(ra, colb)]);
                bh[f] = __builtin_bit_cast(bf16x8, *(const u16x8*)&Bh[swz(rb, colb)]);
                bl[f] = __builtin_bit_cast(bf16x8, *(const u16x8*)&Bl[swz(rb, colb)]);
            }
#pragma unroll
            for (int fr = 0; fr < 4; ++fr)
#pragma unroll
                for (int fc = 0; fc < 4; ++fc) {
                    acc[fr][fc] = __builtin_amdgcn_mfma_f32_16x16x32_bf16(ah[fr], bh[fc], acc[fr][fc], 0, 0, 0);
                    acc[fr][fc] = __builtin_amdgcn_mfma_f32_16x16x32_bf16(ah[fr], bl[fc], acc[fr][fc], 0, 0, 0);
                    acc[fr][fc] = __builtin_amdgcn_mfma_f32_16x16x32_bf16(al[fr], bh[fc], acc[fr][fc], 0, 0, 0);
                }
        }
    }

    const size_t grow0 = (size_t)b * LSEQ + it + wrow;
    float*       arow  = attn + grow0 * LSEQ + jt + wcol;
    const float* mrow  = mask + grow0 * LSEQ + jt + wcol;

    float colm[4];
#pragma unroll
    for (int fc = 0; fc < 4; ++fc) {
        float m = acc[0][fc][0];
#pragma unroll
        for (int fr = 0; fr < 4; ++fr)
#pragma unroll
            for (int r = 0; r < 4; ++r) m = fmaxf(m, acc[fr][fc][r]);
        m = fmaxf(m, __shfl_xor(m, 16, 64));
        m = fmaxf(m, __shfl_xor(m, 32, 64));
        colm[fc] = m;
    }
    float rowm[4][4];
#pragma unroll
    for (int fr = 0; fr < 4; ++fr)
#pragma unroll
        for (int r = 0; r < 4; ++r) {
            float m = fmaxf(fmaxf(acc[fr][0][r], acc[fr][1][r]),
                            fmaxf(acc[fr][2][r], acc[fr][3][r]));
            m = fmaxf(m, __shfl_xor(m, 1, 64));
            m = fmaxf(m, __shfl_xor(m, 2, 64));
            m = fmaxf(m, __shfl_xor(m, 4, 64));
            m = fmaxf(m, __shfl_xor(m, 8, 64));
            rowm[fr][r] = m;
        }

    float cols_[4] = {0.f, 0.f, 0.f, 0.f};
    float rows_[4][4];
#pragma unroll
    for (int fr = 0; fr < 4; ++fr) {
#pragma unroll
        for (int r = 0; r < 4; ++r) {
            const int R = (fr << 4) + (g << 2) + r;
            float rs = 0.f;
#pragma unroll
            for (int fc = 0; fc < 4; ++fc) {
                const int C = (fc << 4) + cl;
                const float x = acc[fr][fc][r];
                arow[(size_t)R * LSEQ + C] = x;
                const float mk = mrow[(size_t)R * LSEQ + C];
                rs        += __expf(x - rowm[fr][r]) * mk;
                cols_[fc] += __expf(x - colm[fc])    * mk;
            }
            rs += __shfl_xor(rs, 1, 64);
            rs += __shfl_xor(rs, 2, 64);
            rs += __shfl_xor(rs, 4, 64);
            rs += __shfl_xor(rs, 8, 64);
            rows_[fr][r] = rs;
        }
    }
#pragma unroll
    for (int fc = 0; fc < 4; ++fc) {
        float s = cols_[fc];
        s += __shfl_xor(s, 16, 64);
        s += __shfl_xor(s, 32, 64);
        cols_[fc] = s;
    }

    const int ti = (blockIdx.y << 1) + (w >> 1);
    const int tj = (blockIdx.x << 1) + (w & 1);
    if (cl == 0) {
        const size_t rbase = (size_t)tj * NROWS + (size_t)b * LSEQ + it + wrow;
#pragma unroll
        for (int fr = 0; fr < 4; ++fr)
#pragma unroll
            for (int r = 0; r < 4; ++r) {
                const int R = (fr << 4) + (g << 2) + r;
                rowMt[rbase + R] = rowm[fr][r];
                rowSt[rbase + R] = rows_[fr][r];
            }
    }
    if (g == 0) {
        const size_t cbase = (size_t)ti * NROWS + (size_t)b * LSEQ + jt + wcol;
#pragma unroll
        for (int fc = 0; fc < 4; ++fc) {
            colMt[cbase + (fc << 4) + cl] = colm[fc];
            colSt[cbase + (fc << 4) + cl] = cols_[fc];
        }
    }
}

// ---------------------------------------------------------------------------
// K2: combine per-tile stats -> global max & sum per row / col. (unchanged)
// ---------------------------------------------------------------------------
__global__ __launch_bounds__(256) void k2_combine(
    const float* __restrict__ rowMt, const float* __restrict__ rowSt,
    const float* __restrict__ colMt, const float* __restrict__ colSt,
    float* __restrict__ rmaxf, float* __restrict__ rsumf,
    float* __restrict__ cmaxf, float* __restrict__ csumf)
{
    const int id = blockIdx.x * 256 + threadIdx.x;   // [0, 2*NROWS)
    const bool isRow = (id < NROWS);
    const int off = isRow ? id : id - NROWS;
    const float* Mt = isRow ? rowMt : colMt;
    const float* St = isRow ? rowSt : colSt;

    float m = -INFINITY;
#pragma unroll
    for (int t = 0; t < NTILE; ++t) m = fmaxf(m, Mt[(size_t)t * NROWS + off]);
    float s = 0.f;
#pragma unroll
    for (int t = 0; t < NTILE; ++t)
        s += St[(size_t)t * NROWS + off] * __expf(Mt[(size_t)t * NROWS + off] - m);

    if (isRow) { rmaxf[off] = m; rsumf[off] = s; }
    else       { cmaxf[off] = m; csumf[off] = s; }
}

// ---------------------------------------------------------------------------
// K3: gating fused with out = gated @ v via bf16x3 MFMA.  Block = 64 q-rows
// x 128 dv (512 blocks, 2/CU).  j swept in 64-chunks: stage Vt chunk to LDS,
// gate prefetched attn/mask regs (exact fp32 gated written in place), split
// g -> bf16 hi/lo in swizzled LDS, prefetch next chunk, then MFMA.
// ---------------------------------------------------------------------------
__global__ __launch_bounds__(256, 2) void k3_gated_out(
    const float* __restrict__ mask,
    const unsigned short* __restrict__ vth, const unsigned short* __restrict__ vtl,
    const float* __restrict__ rmaxf, const float* __restrict__ cmaxf,
    const float* __restrict__ rsumf, const float* __restrict__ csumf,
    float* __restrict__ gated, float* __restrict__ outp)
{
    const int b   = blockIdx.y;
    const int it0 = blockIdx.x * 64;

    __shared__ __attribute__((aligned(16))) unsigned short Gh[64 * 64];   // 8 KB
    __shared__ __attribute__((aligned(16))) unsigned short Gl[64 * 64];
    __shared__ __attribute__((aligned(16))) unsigned short Vh[128 * 64];  // 16 KB
    __shared__ __attribute__((aligned(16))) unsigned short Vl[128 * 64];
    __shared__ float RowM[64], RowIS[64], ColM[64], ColIS[64];

    const int tid  = threadIdx.x;
    const int lane = tid & 63;
    const int w    = tid >> 6;             // wave: dv block w*32
    const int g    = lane >> 4;
    const int cl   = lane & 15;

    if (tid < 64) {
        RowM[tid]  = rmaxf[b * LSEQ + it0 + tid];
        RowIS[tid] = 1.f / (rsumf[b * LSEQ + it0 + tid] + EPSV);
    }

    const int grow = tid >> 2;             // gating row 0..63
    const int gcb  = (tid & 3) << 4;       // gating col base 0,16,32,48
    const int vrow = tid >> 1;             // Vt row (dv) 0..127
    const int vcb  = (tid & 1) << 5;       // 0 / 32

    float*       gb = gated + ((size_t)b * LSEQ + it0) * LSEQ;
    const float* mb = mask  + ((size_t)b * LSEQ + it0) * LSEQ;
    const unsigned short* vhb = vth + ((size_t)b * DDIM + vrow) * LSEQ;
    const unsigned short* vlb = vtl + ((size_t)b * DDIM + vrow) * LSEQ;

    f32x4 acc[4][2];
    const f32x4 zero = {0.f, 0.f, 0.f, 0.f};
#pragma unroll
    for (int i = 0; i < 4; ++i) { acc[i][0] = zero; acc[i][1] = zero; }

    // prefetch attn/mask chunk 0
    float4 xr[4], mr[4];
#pragma unroll
    for (int p = 0; p < 4; ++p) {
        xr[p] = *(const float4*)(gb + (size_t)grow * LSEQ + gcb + p * 4);
        mr[p] = *(const float4*)(mb + (size_t)grow * LSEQ + gcb + p * 4);
    }

#pragma unroll 1
    for (int j0 = 0; j0 < LSEQ; j0 += 64) {
        __syncthreads();                   // prev chunk's LDS fully consumed
        if (tid < 64) {
            ColM[tid]  = cmaxf[b * LSEQ + j0 + tid];
            ColIS[tid] = 1.f / (csumf[b * LSEQ + j0 + tid] + EPSV);
        }
        // stage Vt chunk (L2-hot)
#pragma unroll
        for (int cc = 0; cc < 32; cc += 8) {
            *(u16x8*)&Vh[swz(vrow, vcb + cc)] = *(const u16x8*)(vhb + j0 + vcb + cc);
            *(u16x8*)&Vl[swz(vrow, vcb + cc)] = *(const u16x8*)(vlb + j0 + vcb + cc);
        }
        __syncthreads();                   // ColM/ColIS (+V) visible

        // gate 16 elements, write exact fp32 gated, split to bf16 hi/lo
        const float mrw = RowM[grow], isr = RowIS[grow];
        float gs[16];
#pragma unroll
        for (int p = 0; p < 4; ++p) {
            const float xs[4] = {xr[p].x, xr[p].y, xr[p].z, xr[p].w};
            const float ms[4] = {mr[p].x, mr[p].y, mr[p].z, mr[p].w};
#pragma unroll
            for (int e = 0; e < 4; ++e) {
                const int c = gcb + p * 4 + e;
                gs[p * 4 + e] = ms[e] * __expf(2.f * xs[e] - mrw - ColM[c]) * isr * ColIS[c];
            }
            *(float4*)(gb + (size_t)grow * LSEQ + j0 + gcb + p * 4) =
                make_float4(gs[p * 4], gs[p * 4 + 1], gs[p * 4 + 2], gs[p * 4 + 3]);
        }
#pragma unroll
        for (int cc = 0; cc < 16; cc += 8) {
            u16x8 hh, ll;
#pragma unroll
            for (int e = 0; e < 8; ++e) {
                const unsigned short hb = f2bf(gs[cc + e]);
                hh[e] = hb;
                ll[e] = f2bf(gs[cc + e] - bf2f(hb));
            }
            *(u16x8*)&Gh[swz(grow, gcb + cc)] = hh;
            *(u16x8*)&Gl[swz(grow, gcb + cc)] = ll;
        }
        // prefetch next chunk (hides HBM latency under MFMA below)
        if (j0 + 64 < LSEQ) {
#pragma unroll
            for (int p = 0; p < 4; ++p) {
                xr[p] = *(const float4*)(gb + (size_t)grow * LSEQ + j0 + 64 + gcb + p * 4);
                mr[p] = *(const float4*)(mb + (size_t)grow * LSEQ + j0 + 64 + gcb + p * 4);
            }
        }
        __syncthreads();                   // G visible

#pragma unroll
        for (int ks = 0; ks < 64; ks += 32) {
            const int colb = ks + (g << 3);
            bf16x8 ah[4], al[4], bh[2], bl[2];
#pragma unroll
            for (int f = 0; f < 4; ++f) {
                const int ra = (f << 4) + cl;
                ah[f] = __builtin_bit_cast(bf16x8, *(const u16x8*)&Gh[swz(ra, colb)]);
                al[f] = __builtin_bit_cast(bf16x8, *(const u16x8*)&Gl[swz(ra, colb)]);
            }
#pragma unroll
            for (int f = 0; f < 2; ++f) {
                const int rb = (w << 5) + (f << 4) + cl;
                bh[f] = __builtin_bit_cast(bf16x8, *(const u16x8*)&Vh[swz(rb, colb)]);
                bl[f] = __builtin_bit_cast(bf16x8, *(const u16x8*)&Vl[swz(rb, colb)]);
            }
#pragma unroll
            for (int fr = 0; fr < 4; ++fr)
#pragma unroll
                for (int fc = 0; fc < 2; ++fc) {
                    acc[fr][fc] = __builtin_amdgcn_mfma_f32_16x16x32_bf16(ah[fr], bh[fc], acc[fr][fc], 0, 0, 0);
                    acc[fr][fc] = __builtin_amdgcn_mfma_f32_16x16x32_bf16(al[fr], bh[fc], acc[fr][fc], 0, 0, 0);
                    acc[fr][fc] = __builtin_amdgcn_mfma_f32_16x16x32_bf16(ah[fr], bl[fc], acc[fr][fc], 0, 0, 0);
                }
        }
    }

    // epilogue: C/D layout row = g*4 + r (q-row), col = cl (dv)
    float* ob = outp + ((size_t)b * LSEQ + it0) * DDIM + (w << 5);
#pragma unroll
    for (int fr = 0; fr < 4; ++fr)
#pragma unroll
        for (int r = 0; r < 4; ++r) {
            const int R = (fr << 4) + (g << 2) + r;
#pragma unroll
            for (int fc = 0; fc < 2; ++fc)
                ob[(size_t)R * DDIM + (fc << 4) + cl] = acc[fr][fc][r];
        }
}

// ---------------------------------------------------------------------------
extern "C" void kernel_launch(void* const* d_in, const int* in_sizes, int n_in,
                              void* d_out, int out_size, void* d_ws, size_t ws_size,
                              hipStream_t stream)
{
    (void)in_sizes; (void)n_in; (void)out_size; (void)ws_size;
    const float* q    = (const float*)d_in[0];
    const float* k    = (const float*)d_in[1];
    const float* v    = (const float*)d_in[2];
    const float* mask = (const float*)d_in[3];

    float* outp  = (float*)d_out;                                   // B*L*D
    float* gated = (float*)d_out + (size_t)BATCH * LSEQ * DDIM;     // B*L*L

    float* rowMt = (float*)d_ws;                 // [NTILE][NROWS]
    float* rowSt = rowMt + (size_t)NTILE * NROWS;
    float* colMt = rowSt + (size_t)NTILE * NROWS;
    float* colSt = colMt + (size_t)NTILE * NROWS;
    float* rmaxf = colSt + (size_t)NTILE * NROWS;
    float* rsumf = rmaxf + NROWS;
    float* cmaxf = rsumf + NROWS;
    float* csumf = cmaxf + NROWS;
    unsigned short* vth = (unsigned short*)(csumf + NROWS);          // [B][D][L] bf16-hi
    unsigned short* vtl = vth + (size_t)BATCH * DDIM * LSEQ;         // [B][D][L] bf16-lo

    dim3 g0(LSEQ / 64, DDIM / 64, BATCH);
    k0_vtrans<<<g0, dim3(256), 0, stream>>>(v, vth, vtl);

    dim3 g1(LSEQ / 128, LSEQ / 128, BATCH);
    k1_qk_stats<<<g1, dim3(256), 0, stream>>>(q, k, mask, gated,
                                              rowMt, rowSt, colMt, colSt);

    k2_combine<<<dim3(2 * NROWS / 256), dim3(256), 0, stream>>>(
        rowMt, rowSt, colMt, colSt, rmaxf, rsumf, cmaxf, csumf);

    dim3 g3(LSEQ / 64, BATCH);
    k3_gated_out<<<g3, dim3(256), 0, stream>>>(mask, vth, vtl, rmaxf, cmaxf,
                                               rsumf, csumf, gated, outp);
}

// Round 3
// 693.467 us; speedup vs baseline: 1.2720x; 1.0835x over previous
//
#include <hip/hip_runtime.h>

#define BATCH 16
#define LSEQ  2048
#define DDIM  128
#define EPSV  1e-12f
#define NTILE (LSEQ / 64)          // 32 stat-tiles per dim
#define NROWS (BATCH * LSEQ)       // 32768
#define MASKED_NEG (-1e30f)

typedef __attribute__((ext_vector_type(4))) float f32x4;
typedef __attribute__((ext_vector_type(8))) __bf16 bf16x8;
typedef __attribute__((ext_vector_type(8))) unsigned short u16x8;

__device__ __forceinline__ unsigned short f2bf(float x) {
    unsigned int u = __float_as_uint(x);
    u += 0x7FFFu + ((u >> 16) & 1u);
    return (unsigned short)(u >> 16);
}
__device__ __forceinline__ float bf2f(unsigned short h) {
    return __uint_as_float(((unsigned int)h) << 16);
}

// swizzled offset within a [rows][64 cols] ushort plane (row = 128B = 8 x 16B slots)
// LDS[r][s] holds source slot s^(r&7); reading slot (c>>3)^(r&7) returns column c.
__device__ __forceinline__ int swz(int row, int col8) {   // col8 is 8-aligned
    return (row << 6) + ((((col8 >> 3) ^ row) & 7) << 3);
}

// direct-to-LDS copy of one 16B slot per lane (LDS dest linear, source pre-swizzled)
__device__ __forceinline__ void gll16(const unsigned short* src, unsigned short* ldsdst) {
    __builtin_amdgcn_global_load_lds(
        (const __attribute__((address_space(1))) void*)src,
        (__attribute__((address_space(3))) void*)ldsdst, 16, 0, 0);
}

// ---------------------------------------------------------------------------
// K0a: elementwise fp32 -> bf16 hi/lo split for Q (blockIdx.y=0) and K (=1).
// ---------------------------------------------------------------------------
__global__ __launch_bounds__(256) void k0_split(
    const float* __restrict__ q, const float* __restrict__ kmat,
    unsigned short* __restrict__ qh, unsigned short* __restrict__ ql,
    unsigned short* __restrict__ kh, unsigned short* __restrict__ kl)
{
    const float* s     = blockIdx.y ? kmat : q;
    unsigned short* ph = blockIdx.y ? kh : qh;
    unsigned short* pl = blockIdx.y ? kl : ql;
    const size_t i = ((size_t)blockIdx.x * 256 + threadIdx.x) << 3;
    float xs[8];
    *(float4*)&xs[0] = *(const float4*)(s + i);
    *(float4*)&xs[4] = *(const float4*)(s + i + 4);
    u16x8 hh, ll;
#pragma unroll
    for (int e = 0; e < 8; ++e) {
        const unsigned short h = f2bf(xs[e]);
        hh[e] = h;
        ll[e] = f2bf(xs[e] - bf2f(h));
    }
    *(u16x8*)(ph + i) = hh;
    *(u16x8*)(pl + i) = ll;
}

// ---------------------------------------------------------------------------
// K0b: V[b][j][dv] -> Vt planes (bf16 hi/lo) [b][dv][j]
// ---------------------------------------------------------------------------
__global__ __launch_bounds__(256) void k0_vtrans(
    const float* __restrict__ v,
    unsigned short* __restrict__ vth, unsigned short* __restrict__ vtl)
{
    const int b  = blockIdx.z;
    const int j0 = blockIdx.x * 64;
    const int d0 = blockIdx.y * 64;
    __shared__ float T[64][65];

    const int tid = threadIdx.x;
    {
        const int jr = tid >> 4;
        const int c4 = (tid & 15) << 2;
#pragma unroll
        for (int p = 0; p < 4; ++p) {
            const int row = jr + (p << 4);
            *(float4*)&T[row][c4] =
                *(const float4*)(v + ((size_t)b * LSEQ + j0 + row) * DDIM + d0 + c4);
        }
    }
    __syncthreads();

    const int dr = tid >> 2;
    const int jc = (tid & 3) << 4;
    u16x8 h[2], l[2];
#pragma unroll
    for (int e = 0; e < 16; ++e) {
        const float x = T[jc + e][dr];
        const unsigned short hh = f2bf(x);
        h[e >> 3][e & 7] = hh;
        l[e >> 3][e & 7] = f2bf(x - bf2f(hh));
    }
    unsigned short* oh = vth + ((size_t)b * DDIM + d0 + dr) * LSEQ + j0 + jc;
    unsigned short* ol = vtl + ((size_t)b * DDIM + d0 + dr) * LSEQ + j0 + jc;
    *(u16x8*)oh = h[0]; *(u16x8*)(oh + 8) = h[1];
    *(u16x8*)ol = l[0]; *(u16x8*)(ol + 8) = l[1];
}

// ---------------------------------------------------------------------------
// K1: attn' = masked(Q K^T) via bf16x3 MFMA, global_load_lds staging.
// ---------------------------------------------------------------------------
__global__ __launch_bounds__(256, 2) void k1_qk_stats(
    const unsigned short* __restrict__ qh, const unsigned short* __restrict__ ql,
    const unsigned short* __restrict__ kh, const unsigned short* __restrict__ kl,
    const float* __restrict__ mask, float* __restrict__ attn,
    float* __restrict__ rowMt, float* __restrict__ rowSt,
    float* __restrict__ colMt, float* __restrict__ colSt)
{
    const int b  = blockIdx.z;
    const int it = blockIdx.y * 128;
    const int jt = blockIdx.x * 128;

    __shared__ __attribute__((aligned(16))) unsigned short smem[4 * 128 * 64]; // 64 KB
    unsigned short* Ah = smem;
    unsigned short* Al = smem + 8192;
    unsigned short* Bh = smem + 16384;
    unsigned short* Bl = smem + 24576;

    const int tid  = threadIdx.x;
    const int lane = tid & 63;
    const int w    = tid >> 6;
    const int wrow = (w >> 1) << 6;
    const int wcol = (w & 1) << 6;
    const int g    = lane >> 4;
    const int cl   = lane & 15;

    const unsigned short* splane = (w == 0) ? qh : (w == 1) ? ql : (w == 2) ? kh : kl;
    const size_t srow0 = (size_t)b * LSEQ + ((w < 2) ? it : jt);
    unsigned short* dplane = smem + w * 8192;
    const int srow = lane >> 3;
    const int sslt = lane & 7;

    f32x4 acc[4][4];
    const f32x4 zero = {0.f, 0.f, 0.f, 0.f};
#pragma unroll
    for (int i = 0; i < 4; ++i)
#pragma unroll
        for (int j = 0; j < 4; ++j) acc[i][j] = zero;

    float mreg[4][4][4];
    const float* mrow = mask + ((size_t)b * LSEQ + it + wrow) * LSEQ + jt + wcol;

#pragma unroll
    for (int half = 0; half < 2; ++half) {
        const int ks2 = half << 6;
        if (half) __syncthreads();
#pragma unroll
        for (int qq = 0; qq < 16; ++qq) {
            const int row = (qq << 3) + srow;
            const int ss  = sslt ^ (row & 7);
            gll16(splane + (srow0 + row) * DDIM + ks2 + (ss << 3),
                  dplane + (qq << 9));
        }
        if (half) {
#pragma unroll
            for (int fr = 0; fr < 4; ++fr)
#pragma unroll
                for (int r = 0; r < 4; ++r)
#pragma unroll
                    for (int fc = 0; fc < 4; ++fc)
                        mreg[fr][r][fc] =
                            mrow[(size_t)((fr << 4) + (g << 2) + r) * LSEQ + (fc << 4) + cl];
        }
        __syncthreads();

#pragma unroll
        for (int ks = 0; ks < 64; ks += 32) {
            const int colb = ks + (g << 3);
            bf16x8 ah[4], al[4], bh[4], bl[4];
#pragma unroll
            for (int f = 0; f < 4; ++f) {
                const int ra = wrow + (f << 4) + cl;
                const int rb = wcol + (f << 4) + cl;
                ah[f] = __builtin_bit_cast(bf16x8, *(const u16x8*)&Ah[swz(ra, colb)]);
                al[f] = __builtin_bit_cast(bf16x8, *(const u16x8*)&Al[swz(ra, colb)]);
                bh[f] = __builtin_bit_cast(bf16x8, *(const u16x8*)&Bh[swz(rb, colb)]);
                bl[f] = __builtin_bit_cast(bf16x8, *(const u16x8*)&Bl[swz(rb, colb)]);
            }
#pragma unroll
            for (int fr = 0; fr < 4; ++fr)
#pragma unroll
                for (int fc = 0; fc < 4; ++fc) {
                    acc[fr][fc] = __builtin_amdgcn_mfma_f32_16x16x32_bf16(ah[fr], bh[fc], acc[fr][fc], 0, 0, 0);
                    acc[fr][fc] = __builtin_amdgcn_mfma_f32_16x16x32_bf16(ah[fr], bl[fc], acc[fr][fc], 0, 0, 0);
                    acc[fr][fc] = __builtin_amdgcn_mfma_f32_16x16x32_bf16(al[fr], bh[fc], acc[fr][fc], 0, 0, 0);
                }
        }
    }

    float* arow = attn + ((size_t)b * LSEQ + it + wrow) * LSEQ + jt + wcol;

    float colm[4];
#pragma unroll
    for (int fc = 0; fc < 4; ++fc) {
        float m = acc[0][fc][0];
#pragma unroll
        for (int fr = 0; fr < 4; ++fr)
#pragma unroll
            for (int r = 0; r < 4; ++r) m = fmaxf(m, acc[fr][fc][r]);
        m = fmaxf(m, __shfl_xor(m, 16, 64));
        m = fmaxf(m, __shfl_xor(m, 32, 64));
        colm[fc] = m;
    }
    float rowm[4][4];
#pragma unroll
    for (int fr = 0; fr < 4; ++fr)
#pragma unroll
        for (int r = 0; r < 4; ++r) {
            float m = fmaxf(fmaxf(acc[fr][0][r], acc[fr][1][r]),
                            fmaxf(acc[fr][2][r], acc[fr][3][r]));
            m = fmaxf(m, __shfl_xor(m, 1, 64));
            m = fmaxf(m, __shfl_xor(m, 2, 64));
            m = fmaxf(m, __shfl_xor(m, 4, 64));
            m = fmaxf(m, __shfl_xor(m, 8, 64));
            rowm[fr][r] = m;
        }

    float cols_[4] = {0.f, 0.f, 0.f, 0.f};
    float rows_[4][4];
#pragma unroll
    for (int fr = 0; fr < 4; ++fr) {
#pragma unroll
        for (int r = 0; r < 4; ++r) {
            const int R = (fr << 4) + (g << 2) + r;
            const float rm = rowm[fr][r];
            float rs = 0.f;
#pragma unroll
            for (int fc = 0; fc < 4; ++fc) {
                const int C = (fc << 4) + cl;
                const float x  = acc[fr][fc][r];
                const float xp = (mreg[fr][r][fc] != 0.f) ? x : MASKED_NEG;
                arow[(size_t)R * LSEQ + C] = xp;
                rs        += __expf(xp - rm);
                cols_[fc] += __expf(xp - colm[fc]);
            }
            rs += __shfl_xor(rs, 1, 64);
            rs += __shfl_xor(rs, 2, 64);
            rs += __shfl_xor(rs, 4, 64);
            rs += __shfl_xor(rs, 8, 64);
            rows_[fr][r] = rs;
        }
    }
#pragma unroll
    for (int fc = 0; fc < 4; ++fc) {
        float s = cols_[fc];
        s += __shfl_xor(s, 16, 64);
        s += __shfl_xor(s, 32, 64);
        cols_[fc] = s;
    }

    const int ti = (blockIdx.y << 1) + (w >> 1);
    const int tj = (blockIdx.x << 1) + (w & 1);
    if (cl == 0) {
        const size_t rbase = (size_t)tj * NROWS + (size_t)b * LSEQ + it + wrow;
#pragma unroll
        for (int fr = 0; fr < 4; ++fr)
#pragma unroll
            for (int r = 0; r < 4; ++r) {
                const int R = (fr << 4) + (g << 2) + r;
                rowMt[rbase + R] = rowm[fr][r];
                rowSt[rbase + R] = rows_[fr][r];
            }
    }
    if (g == 0) {
        const size_t cbase = (size_t)ti * NROWS + (size_t)b * LSEQ + jt + wcol;
#pragma unroll
        for (int fc = 0; fc < 4; ++fc) {
            colMt[cbase + (fc << 4) + cl] = colm[fc];
            colSt[cbase + (fc << 4) + cl] = cols_[fc];
        }
    }
}

// ---------------------------------------------------------------------------
// K2: combine per-tile stats -> global max & INVERSE sum per row / col.
// ---------------------------------------------------------------------------
__global__ __launch_bounds__(256) void k2_combine(
    const float* __restrict__ rowMt, const float* __restrict__ rowSt,
    const float* __restrict__ colMt, const float* __restrict__ colSt,
    float* __restrict__ rmaxf, float* __restrict__ rinvf,
    float* __restrict__ cmaxf, float* __restrict__ cinvf)
{
    const int id = blockIdx.x * 256 + threadIdx.x;
    const bool isRow = (id < NROWS);
    const int off = isRow ? id : id - NROWS;
    const float* Mt = isRow ? rowMt : colMt;
    const float* St = isRow ? rowSt : colSt;

    float m = -INFINITY;
#pragma unroll
    for (int t = 0; t < NTILE; ++t) m = fmaxf(m, Mt[(size_t)t * NROWS + off]);
    float s = 0.f;
#pragma unroll
    for (int t = 0; t < NTILE; ++t)
        s += St[(size_t)t * NROWS + off] * __expf(Mt[(size_t)t * NROWS + off] - m);
    const float inv = 1.f / (s + EPSV);

    if (isRow) { rmaxf[off] = m; rinvf[off] = inv; }
    else       { cmaxf[off] = m; cinvf[off] = inv; }
}

// ---------------------------------------------------------------------------
// K3: gated = exp(2x' - mr - mc) * irw * ic, in place; out = gated @ v.
// 32 q-rows x 128 dv per block (grid 1024), 2 barriers per 64-j chunk.
// ---------------------------------------------------------------------------
__global__ __launch_bounds__(256, 3) void k3_gated_out(
    const unsigned short* __restrict__ vth, const unsigned short* __restrict__ vtl,
    const float* __restrict__ rmaxf, const float* __restrict__ cmaxf,
    const float* __restrict__ rinvf, const float* __restrict__ cinvf,
    float* __restrict__ gated, float* __restrict__ outp)
{
    const int b   = blockIdx.y;
    const int it0 = blockIdx.x * 32;

    __shared__ __attribute__((aligned(16))) unsigned short Gh[32 * 64];   // 4 KB
    __shared__ __attribute__((aligned(16))) unsigned short Gl[32 * 64];
    __shared__ __attribute__((aligned(16))) unsigned short Vh[128 * 64];  // 16 KB
    __shared__ __attribute__((aligned(16))) unsigned short Vl[128 * 64];

    const int tid  = threadIdx.x;
    const int lane = tid & 63;
    const int w    = tid >> 6;
    const int g    = lane >> 4;
    const int cl   = lane & 15;

    const int grow = tid >> 3;
    const int gcb  = (tid & 7) << 3;

    const float mrw = rmaxf[b * LSEQ + it0 + grow];
    const float irw = rinvf[b * LSEQ + it0 + grow];

    float* gb = gated + ((size_t)b * LSEQ + it0) * LSEQ;

    unsigned short* vplane_d       = (w >> 1) ? Vl : Vh;
    const unsigned short* vplane_s = (w >> 1) ? vtl : vth;
    const int vrow0 = (w & 1) << 6;
    const int srow  = lane >> 3;
    const int sslt  = lane & 7;

    f32x4 acc[2][2];
    const f32x4 zero = {0.f, 0.f, 0.f, 0.f};
#pragma unroll
    for (int i = 0; i < 2; ++i) { acc[i][0] = zero; acc[i][1] = zero; }

    float4 xn[2], cmn[2], cin[2];
#pragma unroll
    for (int p = 0; p < 2; ++p) {
        xn[p]  = *(const float4*)(gb + (size_t)grow * LSEQ + gcb + (p << 2));
        cmn[p] = *(const float4*)(cmaxf + b * LSEQ + gcb + (p << 2));
        cin[p] = *(const float4*)(cinvf + b * LSEQ + gcb + (p << 2));
    }

#pragma unroll 1
    for (int j0 = 0; j0 < LSEQ; j0 += 64) {
        __syncthreads();                   // MFMA(prev) done with G,V LDS
#pragma unroll
        for (int qq = 0; qq < 8; ++qq) {
            const int row = vrow0 + (qq << 3) + srow;
            const int ss  = sslt ^ (row & 7);
            gll16(vplane_s + ((size_t)b * DDIM + row) * LSEQ + j0 + (ss << 3),
                  vplane_d + (((vrow0 >> 3) + qq) << 9));
        }

        float4 xc[2], cmc[2], cic[2];
#pragma unroll
        for (int p = 0; p < 2; ++p) { xc[p] = xn[p]; cmc[p] = cmn[p]; cic[p] = cin[p]; }
        if (j0 + 64 < LSEQ) {
#pragma unroll
            for (int p = 0; p < 2; ++p) {
                xn[p]  = *(const float4*)(gb + (size_t)grow * LSEQ + j0 + 64 + gcb + (p << 2));
                cmn[p] = *(const float4*)(cmaxf + b * LSEQ + j0 + 64 + gcb + (p << 2));
                cin[p] = *(const float4*)(cinvf + b * LSEQ + j0 + 64 + gcb + (p << 2));
            }
        }

        float gs[8];
#pragma unroll
        for (int p = 0; p < 2; ++p) {
            const float xs[4]  = {xc[p].x, xc[p].y, xc[p].z, xc[p].w};
            const float cms[4] = {cmc[p].x, cmc[p].y, cmc[p].z, cmc[p].w};
            const float cis[4] = {cic[p].x, cic[p].y, cic[p].z, cic[p].w};
#pragma unroll
            for (int e = 0; e < 4; ++e)
                gs[(p << 2) + e] = __expf(2.f * xs[e] - mrw - cms[e]) * irw * cis[e];
            *(float4*)(gb + (size_t)grow * LSEQ + j0 + gcb + (p << 2)) =
                make_float4(gs[(p << 2)], gs[(p << 2) + 1], gs[(p << 2) + 2], gs[(p << 2) + 3]);
        }
        u16x8 hh, ll;
#pragma unroll
        for (int e = 0; e < 8; ++e) {
            const unsigned short hb = f2bf(gs[e]);
            hh[e] = hb;
            ll[e] = f2bf(gs[e] - bf2f(hb));
        }
        *(u16x8*)&Gh[swz(grow, gcb)] = hh;
        *(u16x8*)&Gl[swz(grow, gcb)] = ll;

        __syncthreads();                   // G visible + V gll drained

#pragma unroll
        for (int ks = 0; ks < 64; ks += 32) {
            const int colb = ks + (g << 3);
            bf16x8 ah[2], al[2], bh[2], bl[2];
#pragma unroll
            for (int f = 0; f < 2; ++f) {
                const int ra = (f << 4) + cl;
                ah[f] = __builtin_bit_cast(bf16x8, *(const u16x8*)&Gh[swz(ra, colb)]);
                al[f] = __builtin_bit_cast(bf16x8, *(const u16x8*)&Gl[swz(ra, colb)]);
                const int rb = (w << 5) + (f << 4) + cl;
                bh[f] = __builtin_bit_cast(bf16x8, *(const u16x8*)&Vh[swz(rb, colb)]);
                bl[f] = __builtin_bit_cast(bf16x8, *(const u16x8*)&Vl[swz(rb, colb)]);
            }
#pragma unroll
            for (int fr = 0; fr < 2; ++fr)
#pragma unroll
                for (int fc = 0; fc < 2; ++fc) {
                    acc[fr][fc] = __builtin_amdgcn_mfma_f32_16x16x32_bf16(ah[fr], bh[fc], acc[fr][fc], 0, 0, 0);
                    acc[fr][fc] = __builtin_amdgcn_mfma_f32_16x16x32_bf16(al[fr], bh[fc], acc[fr][fc], 0, 0, 0);
                    acc[fr][fc] = __builtin_amdgcn_mfma_f32_16x16x32_bf16(ah[fr], bl[fc], acc[fr][fc], 0, 0, 0);
                }
        }
    }

    float* ob = outp + ((size_t)b * LSEQ + it0) * DDIM + (w << 5);
#pragma unroll
    for (int fr = 0; fr < 2; ++fr)
#pragma unroll
        for (int r = 0; r < 4; ++r) {
            const int R = (fr << 4) + (g << 2) + r;
#pragma unroll
            for (int fc = 0; fc < 2; ++fc)
                ob[(size_t)R * DDIM + (fc << 4) + cl] = acc[fr][fc][r];
        }
}

// ---------------------------------------------------------------------------
extern "C" void kernel_launch(void* const* d_in, const int* in_sizes, int n_in,
                              void* d_out, int out_size, void* d_ws, size_t ws_size,
                              hipStream_t stream)
{
    (void)in_sizes; (void)n_in; (void)out_size; (void)ws_size;
    const float* q    = (const float*)d_in[0];
    const float* k    = (const float*)d_in[1];
    const float* v    = (const float*)d_in[2];
    const float* mask = (const float*)d_in[3];

    float* outp  = (float*)d_out;                                   // B*L*D
    float* gated = (float*)d_out + (size_t)BATCH * LSEQ * DDIM;     // B*L*L

    float* rowMt = (float*)d_ws;                 // [NTILE][NROWS]
    float* rowSt = rowMt + (size_t)NTILE * NROWS;
    float* colMt = rowSt + (size_t)NTILE * NROWS;
    float* colSt = colMt + (size_t)NTILE * NROWS;
    float* rmaxf = colSt + (size_t)NTILE * NROWS;
    float* rinvf = rmaxf + NROWS;
    float* cmaxf = rinvf + NROWS;
    float* cinvf = cmaxf + NROWS;
    unsigned short* vth = (unsigned short*)(cinvf + NROWS);          // [B][D][L]
    unsigned short* vtl = vth + (size_t)BATCH * DDIM * LSEQ;
    unsigned short* qhp = vtl + (size_t)BATCH * DDIM * LSEQ;         // [B][L][D]
    unsigned short* qlp = qhp + (size_t)BATCH * LSEQ * DDIM;
    unsigned short* khp = qlp + (size_t)BATCH * LSEQ * DDIM;
    unsigned short* klp = khp + (size_t)BATCH * LSEQ * DDIM;

    dim3 gsplit((BATCH * LSEQ * DDIM) / 2048, 2);
    k0_split<<<gsplit, dim3(256), 0, stream>>>(q, k, qhp, qlp, khp, klp);

    dim3 g0(LSEQ / 64, DDIM / 64, BATCH);
    k0_vtrans<<<g0, dim3(256), 0, stream>>>(v, vth, vtl);

    dim3 g1(LSEQ / 128, LSEQ / 128, BATCH);
    k1_qk_stats<<<g1, dim3(256), 0, stream>>>(qhp, qlp, khp, klp, mask, gated,
                                              rowMt, rowSt, colMt, colSt);

    k2_combine<<<dim3(2 * NROWS / 256), dim3(256), 0, stream>>>(
        rowMt, rowSt, colMt, colSt, rmaxf, rinvf, cmaxf, cinvf);

    dim3 g3(LSEQ / 32, BATCH);
    k3_gated_out<<<g3, dim3(256), 0, stream>>>(vth, vtl, rmaxf, cmaxf,
                                               rinvf, cinvf, gated, outp);
}